// Round 7
// baseline (24094.447 us; speedup 1.0000x reference)
//
#include <hip/hip_runtime.h>
#include <math.h>

#define TOK   16384
#define HID   2048
#define INTER 8192
#define NPART 8

typedef __attribute__((ext_vector_type(8))) short short8;
typedef __attribute__((ext_vector_type(4))) float f32x4;

__device__ inline ushort f2bf(float f){
  union{float f; unsigned u;} v; v.f=f;
  unsigned r = v.u + 0x7FFFu + ((v.u>>16)&1u);
  return (ushort)(r>>16);
}

// ---------------- fp32 -> bf16 convert (row-major copy) ----------------
__global__ __launch_bounds__(256) void cvt_f32_bf16(const float* __restrict__ in,
                                                    ushort* __restrict__ out, int n4)
{
  int idx = blockIdx.x*blockDim.x + threadIdx.x;
  int stride = gridDim.x*blockDim.x;
  for (int i = idx; i < n4; i += stride) {
    float4 v = ((const float4*)in)[i];
    ushort4 o;
    o.x = f2bf(v.x); o.y = f2bf(v.y); o.z = f2bf(v.z); o.w = f2bf(v.w);
    ((ushort4*)out)[i] = o;
  }
}

// ---------------- pack W[K][N] f32 -> B-fragment-linear bf16 ----------------
// out[((nt*(K/32) + ks)*64 + l)*8 + j] = W[ks*32 + (l>>4)*8 + j][nt*16 + (l&15)]
__global__ __launch_bounds__(256) void pack_b(const float* __restrict__ W,
                                              ushort* __restrict__ out,
                                              int N, int k5sh, int total)
{
  int tid = blockIdx.x*256 + threadIdx.x;
  if (tid >= total) return;
  int l = tid & 63, g = tid >> 6;
  int ks = g & ((1 << k5sh) - 1), nt = g >> k5sh;
  int col = nt*16 + (l & 15);
  int kb  = ks*32 + ((l >> 4) << 3);
  ushort4 o0, o1;
  o0.x = f2bf(W[(size_t)(kb+0)*N + col]);
  o0.y = f2bf(W[(size_t)(kb+1)*N + col]);
  o0.z = f2bf(W[(size_t)(kb+2)*N + col]);
  o0.w = f2bf(W[(size_t)(kb+3)*N + col]);
  o1.x = f2bf(W[(size_t)(kb+4)*N + col]);
  o1.y = f2bf(W[(size_t)(kb+5)*N + col]);
  o1.z = f2bf(W[(size_t)(kb+6)*N + col]);
  o1.w = f2bf(W[(size_t)(kb+7)*N + col]);
  ((ushort4*)(out + (size_t)tid*8))[0] = o0;
  ((ushort4*)(out + (size_t)tid*8))[1] = o1;
}

// ---------------- pack W[K][16] f32 -> B-fragment layout bf16 (LoRA) ----------------
__global__ __launch_bounds__(256) void pack_w(const float* __restrict__ W,
                                              ushort* __restrict__ out, int K)
{
  int tid = blockIdx.x*256 + threadIdx.x;
  int n = (K >> 5) * 64;
  if (tid >= n) return;
  int step = tid >> 6, l = tid & 63;
  int col = l & 15, kb = step*32 + ((l >> 4) << 3);
  ushort4 o0, o1;
  o0.x = f2bf(W[(size_t)(kb+0)*16 + col]);
  o0.y = f2bf(W[(size_t)(kb+1)*16 + col]);
  o0.z = f2bf(W[(size_t)(kb+2)*16 + col]);
  o0.w = f2bf(W[(size_t)(kb+3)*16 + col]);
  o1.x = f2bf(W[(size_t)(kb+4)*16 + col]);
  o1.y = f2bf(W[(size_t)(kb+5)*16 + col]);
  o1.z = f2bf(W[(size_t)(kb+6)*16 + col]);
  o1.w = f2bf(W[(size_t)(kb+7)*16 + col]);
  ((ushort4*)(out + (size_t)tid*8))[0] = o0;
  ((ushort4*)(out + (size_t)tid*8))[1] = o1;
}

// ---------------- rank-16 contract via MFMA, split-K partials ----------------
__global__ __launch_bounds__(256) void lora_in_mfma(const ushort* __restrict__ x,
                                                    const ushort* __restrict__ Wpk,
                                                    float* __restrict__ tpart,
                                                    int M, int K)
{
  const int l  = threadIdx.x & 63;
  const int wv = threadIdx.x >> 6;
  const int jid = blockIdx.x*4 + wv;
  const int nt = M >> 4;
  const int part = jid >> 10;
  const int tile = jid & (nt - 1);
  const int Kc = K / NPART;
  const int k0 = part * Kc;
  const int fr = l & 15, fq = l >> 4;

  const ushort* xp = x + (size_t)(tile*16 + fr)*K + k0 + fq*8;
  const ushort* wp = Wpk + (size_t)(k0 >> 5)*512 + l*8;

  f32x4 acc = (f32x4){0.f,0.f,0.f,0.f};
  const int ns = Kc >> 5;
  for (int s = 0; s < ns; ++s) {
    short8 av = *(const short8*)(xp + s*32);
    short8 bv = *(const short8*)(wp + s*512);
    acc = __builtin_amdgcn_mfma_f32_16x16x32_bf16(av, bv, acc, 0, 0, 0);
  }
  float* o = tpart + ((size_t)part*M + tile*16)*16;
  #pragma unroll
  for (int r = 0; r < 4; ++r) o[(fq*4 + r)*16 + fr] = acc[r];
}

// ---------------- rank-16 expand: out[N][W] = (sum_p tpart[p]) @ Bm[16][W] ----------------
__global__ __launch_bounds__(256) void lora_out(const float* __restrict__ tpart,
                                                const float* __restrict__ Bm,
                                                float* __restrict__ out, int W, int M)
{
  __shared__ float ts[8][16];
  int tid = threadIdx.x;
  int n0 = blockIdx.y*8, i0 = blockIdx.x*1024;
  if (tid < 128) {
    float s = 0.f;
    #pragma unroll
    for (int p = 0; p < NPART; ++p)
      s += tpart[((size_t)p*M + n0 + (tid>>4))*16 + (tid&15)];
    ts[tid>>4][tid&15] = s;
  }
  __syncthreads();
  const float4* B4 = (const float4*)Bm;
  float4 breg[16];
  #pragma unroll
  for (int r = 0; r < 16; r++) breg[r] = B4[(size_t)r*(W>>2) + (i0>>2) + tid];
  #pragma unroll
  for (int n = 0; n < 8; n++) {
    float4 o; o.x = o.y = o.z = o.w = 0.f;
    #pragma unroll
    for (int r = 0; r < 16; r++) {
      float s = ts[n][r];
      o.x += s*breg[r].x; o.y += s*breg[r].y; o.z += s*breg[r].z; o.w += s*breg[r].w;
    }
    ((float4*)(out + (size_t)(n0+n)*W + i0))[tid] = o;
  }
}

// =====================================================================
// 256x256 bf16 MFMA GEMM, BK=32, 8 waves (2Mx4N).
// A: LDS ring-4 (64 KB, A-only) via global_load_lds.
// B: fragment-packed global->register loads (L2/L3-resident weights).
// Cross-tile register read-ahead, 1 barrier + counted vmcnt per tile,
// XOR swizzle on A, setprio, swapped-operand vectorized stores.
// 2 blocks/CU (64 KB LDS, VGPR<=128).
// C = A[M][K] @ Bpk + bias.  EPI=0: gelu->bf16; EPI=1: f32.
// =====================================================================
template<int EPI>
__global__ __launch_bounds__(512, 4)
void gemm_bt(const ushort* __restrict__ A,
             const ushort* __restrict__ BP,
             const float* __restrict__ bias,
             ushort* __restrict__ outb,
             float* __restrict__ outf,
             int M, int N, int K, int grid_n)
{
  __shared__ __align__(16) ushort lds[4][8192];   // [ring][A 256x32]

  const int tid = threadIdx.x;
  const int l   = tid & 63;
  const int w   = tid >> 6;
  const int wr  = w >> 2;            // 0..1
  const int wc  = w & 3;             // 0..3

  const int nwg = gridDim.x;
  const int cpx = nwg >> 3;
  const int bid = blockIdx.x;
  const int wg  = (bid & 7) * cpx + (bid >> 3);
  const int bx  = wg % grid_n;
  const int by  = wg / grid_n;

  // A staging: global side carries the inverse swizzle
  const int srow = w*32 + (l >> 2);
  const int scol = (((l & 3) ^ ((l >> 3) & 3)) << 3);
  const ushort* agp = A + (size_t)(by*256 + srow)*K + scol;
  const int ldso = w*1024;

  // fragment read offsets
  const int fr  = l & 15, fq = l >> 4;
  const int swz = fq ^ ((fr >> 1) & 3);
  const int aoff = (wr*128 + fr)*32 + swz*8;
  const int K5 = K >> 5;
  // packed B base for this wave's 4 n-frags
  const ushort* bq = BP + ((size_t)(bx*16 + wc*4)*K5)*512 + l*8;

  f32x4 acc[8][4];
  #pragma unroll
  for (int m = 0; m < 8; m++)
    #pragma unroll
    for (int n = 0; n < 4; n++) acc[m][n] = (f32x4){0.f,0.f,0.f,0.f};

  auto stageA = [&](int kt) {
    const int c = kt & 3;
    #pragma unroll
    for (int j = 0; j < 2; ++j)
      __builtin_amdgcn_global_load_lds(
        (const __attribute__((address_space(1))) void*)(agp + (size_t)(j*16)*K + (size_t)kt*32),
        (__attribute__((address_space(3))) void*)(&lds[c][ldso + j*512]), 16, 0, 0);
  };

  short8 a0[8], b0[4], a1[8], b1[4];

#define AREADS(AS, c) do {                                               \
    const ushort* Ab_ = &lds[c][0];                                      \
    _Pragma("unroll")                                                    \
    for (int m_ = 0; m_ < 8; ++m_) AS[m_] = *(const short8*)(Ab_ + aoff + m_*512); \
  } while (0)

#define BGLOAD(BS, kt) do {                                              \
    _Pragma("unroll")                                                    \
    for (int n_ = 0; n_ < 4; ++n_)                                       \
      BS[n_] = *(const short8*)(bq + ((size_t)n_*K5 + (kt))*512);        \
  } while (0)

#define MFMA32(AS, BS) do {                                              \
    __builtin_amdgcn_s_setprio(1);                                       \
    _Pragma("unroll")                                                    \
    for (int m_ = 0; m_ < 8; ++m_)                                       \
      _Pragma("unroll")                                                  \
      for (int n_ = 0; n_ < 4; ++n_)                                     \
        acc[m_][n_] = __builtin_amdgcn_mfma_f32_16x16x32_bf16(BS[n_], AS[m_], acc[m_][n_], 0,0,0); \
    __builtin_amdgcn_s_setprio(0);                                       \
  } while (0)

  const int nk = K >> 5;   // even, >= 4

  // prologue: Bg(0)->b0 (4), stageA(0) (2), stageA(1) (2); certify Bg(0)+stA(0)
  BGLOAD(b0, 0);
  stageA(0); stageA(1);
  asm volatile("s_waitcnt vmcnt(2)" ::: "memory");
  __builtin_amdgcn_s_barrier();
  asm volatile("" ::: "memory");
  AREADS(a0, 0);

  for (int kt = 0; kt < nk; kt += 2) {
    // ---- even tile kt: issue stA(kt+2), Bg(kt+1); certify stA(kt+1)+Bg(kt) ----
    if (kt + 2 < nk) stageA(kt + 2);
    BGLOAD(b1, kt + 1);
    if (kt + 2 < nk) asm volatile("s_waitcnt vmcnt(6)" ::: "memory");
    else             asm volatile("s_waitcnt vmcnt(4)" ::: "memory");
    __builtin_amdgcn_s_barrier();
    asm volatile("" ::: "memory");
    AREADS(a1, (kt+1) & 3);
    __builtin_amdgcn_sched_barrier(0);
    MFMA32(a0, b0);

    // ---- odd tile kt+1: issue stA(kt+3), Bg(kt+2); certify stA(kt+2)+Bg(kt+1) ----
    if (kt + 2 < nk) {
      if (kt + 3 < nk) stageA(kt + 3);
      BGLOAD(b0, kt + 2);
      if (kt + 3 < nk) asm volatile("s_waitcnt vmcnt(6)" ::: "memory");
      else             asm volatile("s_waitcnt vmcnt(4)" ::: "memory");
      __builtin_amdgcn_s_barrier();
      asm volatile("" ::: "memory");
      AREADS(a0, (kt+2) & 3);
      __builtin_amdgcn_sched_barrier(0);
    } else {
      asm volatile("s_waitcnt vmcnt(0)" ::: "memory");
      __builtin_amdgcn_s_barrier();
      asm volatile("" ::: "memory");
    }
    MFMA32(a1, b1);
  }

#undef AREADS
#undef BGLOAD
#undef MFMA32

  // ---- epilogue: lane&15 = M-row, (lane>>4)*4+r = N-col -> vector stores ----
  #pragma unroll
  for (int m = 0; m < 8; ++m) {
    const int rowg = by*256 + wr*128 + m*16 + fr;
    #pragma unroll
    for (int n = 0; n < 4; ++n) {
      const int colg = bx*256 + wc*64 + n*16 + fq*4;
      const float4 bv = *(const float4*)&bias[colg];
      float v0 = acc[m][n][0] + bv.x;
      float v1 = acc[m][n][1] + bv.y;
      float v2 = acc[m][n][2] + bv.z;
      float v3 = acc[m][n][3] + bv.w;
      if (EPI == 0) {
        #define GELU(v) do { \
          float u_ = 0.7978845608028654f*((v) + 0.044715f*(v)*(v)*(v)); \
          float e_ = __builtin_amdgcn_exp2f(-2.8853900817779268f*u_);   \
          (v) = (v) * __builtin_amdgcn_rcpf(1.0f + e_); } while(0)
        GELU(v0); GELU(v1); GELU(v2); GELU(v3);
        #undef GELU
        ushort4 o; o.x = f2bf(v0); o.y = f2bf(v1); o.z = f2bf(v2); o.w = f2bf(v3);
        *(ushort4*)&outb[(size_t)rowg*N + colg] = o;
      } else {
        float4 o; o.x = v0; o.y = v1; o.z = v2; o.w = v3;
        *(float4*)&outf[(size_t)rowg*N + colg] = o;
      }
    }
  }
}

extern "C" void kernel_launch(void* const* d_in, const int* in_sizes, int n_in,
                              void* d_out, int out_size, void* d_ws, size_t ws_size,
                              hipStream_t stream)
{
  const float* hid  = (const float*)d_in[0];
  const float* Wfc  = (const float*)d_in[1];
  const float* bfc  = (const float*)d_in[2];
  const float* Wpj  = (const float*)d_in[3];
  const float* bpj  = (const float*)d_in[4];
  const float* Amat = (const float*)d_in[5];
  const float* Bmat = (const float*)d_in[6];
  const float* Cmat = (const float*)d_in[7];
  const float* Dmat = (const float*)d_in[8];

  float* out = (float*)d_out;                  // [TOK][HID]
  float* ab  = out + (size_t)TOK*HID;          // [TOK][INTER]
  float* cd  = ab  + (size_t)TOK*INTER;        // [TOK][HID]

  char* ws = (char*)d_ws;
  ushort* hidb = (ushort*)ws;  ws += (size_t)TOK*HID*2;
  ushort* bpk1 = (ushort*)ws;  ws += (size_t)HID*INTER*2;   // packed W_fc
  ushort* bpk2 = (ushort*)ws;  ws += (size_t)INTER*HID*2;   // packed W_proj
  ushort* hbf  = (ushort*)ws;  ws += (size_t)TOK*INTER*2;
  ushort* apk  = (ushort*)ws;  ws += (size_t)HID*16*2;
  ushort* cpk  = (ushort*)ws;  ws += (size_t)INTER*16*2;
  float*  tpab = (float*)ws;   ws += (size_t)NPART*TOK*16*4;
  float*  tpcd = (float*)ws;   ws += (size_t)NPART*TOK*16*4;

  // independent pre-passes
  cvt_f32_bf16<<<4096, 256, 0, stream>>>(hid, hidb, TOK*HID/4);
  {
    int tot1 = (INTER/16)*(HID/32)*64;   // pack W_fc [HID][INTER], K=HID (k5sh=6)
    pack_b<<<(tot1 + 255)/256, 256, 0, stream>>>(Wfc, bpk1, INTER, 6, tot1);
    int tot2 = (HID/16)*(INTER/32)*64;   // pack W_proj [INTER][HID], K=INTER (k5sh=8)
    pack_b<<<(tot2 + 255)/256, 256, 0, stream>>>(Wpj, bpk2, HID, 8, tot2);
  }
  pack_w<<<((HID/32)*64 + 255)/256, 256, 0, stream>>>(Amat, apk, HID);
  pack_w<<<((INTER/32)*64 + 255)/256, 256, 0, stream>>>(Cmat, cpk, INTER);

  // t_ab partials = hidden @ A
  lora_in_mfma<<<(TOK/16)*NPART/4, 256, 0, stream>>>(hidb, apk, tpab, TOK, HID);

  // h = gelu(hidden @ W_fc + b_fc), stored bf16
  gemm_bt<0><<<(TOK/256)*(INTER/256), 512, 0, stream>>>(
      hidb, bpk1, bfc, hbf, nullptr, TOK, INTER, HID, INTER/256);

  // ab_out = (hidden @ A) @ B
  lora_out<<<dim3(INTER/1024, TOK/8), 256, 0, stream>>>(tpab, Bmat, ab, INTER, TOK);

  // cd_out = (h @ C) @ D
  lora_in_mfma<<<(TOK/16)*NPART/4, 256, 0, stream>>>(hbf, cpk, tpcd, TOK, INTER);
  lora_out<<<dim3(HID/1024, TOK/8), 256, 0, stream>>>(tpcd, Dmat, cd, HID, TOK);

  // out = h @ W_proj + b_proj
  gemm_bt<1><<<(TOK/256)*(HID/256), 512, 0, stream>>>(
      hbf, bpk2, bpj, nullptr, out, TOK, HID, INTER, HID/256);
}

// Round 8
// 1490.665 us; speedup vs baseline: 16.1636x; 16.1636x over previous
//
#include <hip/hip_runtime.h>
#include <math.h>

#define TOK   16384
#define HID   2048
#define INTER 8192
#define NPART 8

typedef __attribute__((ext_vector_type(8))) short short8;
typedef __attribute__((ext_vector_type(4))) float f32x4;

__device__ inline ushort f2bf(float f){
  union{float f; unsigned u;} v; v.f=f;
  unsigned r = v.u + 0x7FFFu + ((v.u>>16)&1u);
  return (ushort)(r>>16);
}

// ---------------- fp32 -> bf16 convert (row-major copy) ----------------
__global__ __launch_bounds__(256) void cvt_f32_bf16(const float* __restrict__ in,
                                                    ushort* __restrict__ out, int n4)
{
  int idx = blockIdx.x*blockDim.x + threadIdx.x;
  int stride = gridDim.x*blockDim.x;
  for (int i = idx; i < n4; i += stride) {
    float4 v = ((const float4*)in)[i];
    ushort4 o;
    o.x = f2bf(v.x); o.y = f2bf(v.y); o.z = f2bf(v.z); o.w = f2bf(v.w);
    ((ushort4*)out)[i] = o;
  }
}

// ---------------- pack W[K][N] f32 -> B-fragment-linear bf16 ----------------
// out[((nt*(K/32) + ks)*64 + l)*8 + j] = W[ks*32 + (l>>4)*8 + j][nt*16 + (l&15)]
__global__ __launch_bounds__(256) void pack_b(const float* __restrict__ W,
                                              ushort* __restrict__ out,
                                              int N, int k5sh, int total)
{
  int tid = blockIdx.x*256 + threadIdx.x;
  if (tid >= total) return;
  int l = tid & 63, g = tid >> 6;
  int ks = g & ((1 << k5sh) - 1), nt = g >> k5sh;
  int col = nt*16 + (l & 15);
  int kb  = ks*32 + ((l >> 4) << 3);
  ushort4 o0, o1;
  o0.x = f2bf(W[(size_t)(kb+0)*N + col]);
  o0.y = f2bf(W[(size_t)(kb+1)*N + col]);
  o0.z = f2bf(W[(size_t)(kb+2)*N + col]);
  o0.w = f2bf(W[(size_t)(kb+3)*N + col]);
  o1.x = f2bf(W[(size_t)(kb+4)*N + col]);
  o1.y = f2bf(W[(size_t)(kb+5)*N + col]);
  o1.z = f2bf(W[(size_t)(kb+6)*N + col]);
  o1.w = f2bf(W[(size_t)(kb+7)*N + col]);
  ((ushort4*)(out + (size_t)tid*8))[0] = o0;
  ((ushort4*)(out + (size_t)tid*8))[1] = o1;
}

// ---------------- pack W[K][16] f32 -> B-fragment layout bf16 (LoRA) ----------------
__global__ __launch_bounds__(256) void pack_w(const float* __restrict__ W,
                                              ushort* __restrict__ out, int K)
{
  int tid = blockIdx.x*256 + threadIdx.x;
  int n = (K >> 5) * 64;
  if (tid >= n) return;
  int step = tid >> 6, l = tid & 63;
  int col = l & 15, kb = step*32 + ((l >> 4) << 3);
  ushort4 o0, o1;
  o0.x = f2bf(W[(size_t)(kb+0)*16 + col]);
  o0.y = f2bf(W[(size_t)(kb+1)*16 + col]);
  o0.z = f2bf(W[(size_t)(kb+2)*16 + col]);
  o0.w = f2bf(W[(size_t)(kb+3)*16 + col]);
  o1.x = f2bf(W[(size_t)(kb+4)*16 + col]);
  o1.y = f2bf(W[(size_t)(kb+5)*16 + col]);
  o1.z = f2bf(W[(size_t)(kb+6)*16 + col]);
  o1.w = f2bf(W[(size_t)(kb+7)*16 + col]);
  ((ushort4*)(out + (size_t)tid*8))[0] = o0;
  ((ushort4*)(out + (size_t)tid*8))[1] = o1;
}

// ---------------- rank-16 contract via MFMA, split-K partials ----------------
__global__ __launch_bounds__(256) void lora_in_mfma(const ushort* __restrict__ x,
                                                    const ushort* __restrict__ Wpk,
                                                    float* __restrict__ tpart,
                                                    int M, int K)
{
  const int l  = threadIdx.x & 63;
  const int wv = threadIdx.x >> 6;
  const int jid = blockIdx.x*4 + wv;
  const int nt = M >> 4;
  const int part = jid >> 10;
  const int tile = jid & (nt - 1);
  const int Kc = K / NPART;
  const int k0 = part * Kc;
  const int fr = l & 15, fq = l >> 4;

  const ushort* xp = x + (size_t)(tile*16 + fr)*K + k0 + fq*8;
  const ushort* wp = Wpk + (size_t)(k0 >> 5)*512 + l*8;

  f32x4 acc = (f32x4){0.f,0.f,0.f,0.f};
  const int ns = Kc >> 5;
  for (int s = 0; s < ns; ++s) {
    short8 av = *(const short8*)(xp + s*32);
    short8 bv = *(const short8*)(wp + s*512);
    acc = __builtin_amdgcn_mfma_f32_16x16x32_bf16(av, bv, acc, 0, 0, 0);
  }
  float* o = tpart + ((size_t)part*M + tile*16)*16;
  #pragma unroll
  for (int r = 0; r < 4; ++r) o[(fq*4 + r)*16 + fr] = acc[r];
}

// ---------------- rank-16 expand: out[N][W] = (sum_p tpart[p]) @ Bm[16][W] ----------------
__global__ __launch_bounds__(256) void lora_out(const float* __restrict__ tpart,
                                                const float* __restrict__ Bm,
                                                float* __restrict__ out, int W, int M)
{
  __shared__ float ts[8][16];
  int tid = threadIdx.x;
  int n0 = blockIdx.y*8, i0 = blockIdx.x*1024;
  if (tid < 128) {
    float s = 0.f;
    #pragma unroll
    for (int p = 0; p < NPART; ++p)
      s += tpart[((size_t)p*M + n0 + (tid>>4))*16 + (tid&15)];
    ts[tid>>4][tid&15] = s;
  }
  __syncthreads();
  const float4* B4 = (const float4*)Bm;
  float4 breg[16];
  #pragma unroll
  for (int r = 0; r < 16; r++) breg[r] = B4[(size_t)r*(W>>2) + (i0>>2) + tid];
  #pragma unroll
  for (int n = 0; n < 8; n++) {
    float4 o; o.x = o.y = o.z = o.w = 0.f;
    #pragma unroll
    for (int r = 0; r < 16; r++) {
      float s = ts[n][r];
      o.x += s*breg[r].x; o.y += s*breg[r].y; o.z += s*breg[r].z; o.w += s*breg[r].w;
    }
    ((float4*)(out + (size_t)(n0+n)*W + i0))[tid] = o;
  }
}

// =====================================================================
// 256x256 bf16 MFMA GEMM, BK=32, 8 waves (2Mx4N).
// A: LDS ring-4 (64 KB, A-only) via global_load_lds.
// B: fragment-packed global->register loads (L2/L3-resident weights).
// Cross-tile register read-ahead, 1 barrier + counted vmcnt per tile,
// XOR swizzle on A, setprio, swapped-operand vectorized stores.
// launch_bounds (512,2): full register budget, no spill (R7 lesson).
// C = A[M][K] @ Bpk + bias.  EPI=0: gelu->bf16; EPI=1: f32.
// =====================================================================
template<int EPI>
__global__ __launch_bounds__(512, 2)
void gemm_bt(const ushort* __restrict__ A,
             const ushort* __restrict__ BP,
             const float* __restrict__ bias,
             ushort* __restrict__ outb,
             float* __restrict__ outf,
             int M, int N, int K, int grid_n)
{
  __shared__ __align__(16) ushort lds[4][8192];   // [ring][A 256x32]

  const int tid = threadIdx.x;
  const int l   = tid & 63;
  const int w   = tid >> 6;
  const int wr  = w >> 2;            // 0..1
  const int wc  = w & 3;             // 0..3

  const int nwg = gridDim.x;
  const int cpx = nwg >> 3;
  const int bid = blockIdx.x;
  const int wg  = (bid & 7) * cpx + (bid >> 3);
  const int bx  = wg % grid_n;
  const int by  = wg / grid_n;

  // A staging: global side carries the inverse swizzle
  const int srow = w*32 + (l >> 2);
  const int scol = (((l & 3) ^ ((l >> 3) & 3)) << 3);
  const ushort* agp = A + (size_t)(by*256 + srow)*K + scol;
  const int ldso = w*1024;

  // fragment read offsets
  const int fr  = l & 15, fq = l >> 4;
  const int swz = fq ^ ((fr >> 1) & 3);
  const int aoff = (wr*128 + fr)*32 + swz*8;
  const int K5 = K >> 5;
  // packed B base for this wave's 4 n-frags
  const ushort* bq = BP + ((size_t)(bx*16 + wc*4)*K5)*512 + l*8;

  f32x4 acc[8][4];
  #pragma unroll
  for (int m = 0; m < 8; m++)
    #pragma unroll
    for (int n = 0; n < 4; n++) acc[m][n] = (f32x4){0.f,0.f,0.f,0.f};

  auto stageA = [&](int kt) {
    const int c = kt & 3;
    #pragma unroll
    for (int j = 0; j < 2; ++j)
      __builtin_amdgcn_global_load_lds(
        (const __attribute__((address_space(1))) void*)(agp + (size_t)(j*16)*K + (size_t)kt*32),
        (__attribute__((address_space(3))) void*)(&lds[c][ldso + j*512]), 16, 0, 0);
  };

  short8 a0[8], b0[4], a1[8], b1[4];

#define AREADS(AS, c) do {                                               \
    const ushort* Ab_ = &lds[c][0];                                      \
    _Pragma("unroll")                                                    \
    for (int m_ = 0; m_ < 8; ++m_) AS[m_] = *(const short8*)(Ab_ + aoff + m_*512); \
  } while (0)

#define BGLOAD(BS, kt) do {                                              \
    _Pragma("unroll")                                                    \
    for (int n_ = 0; n_ < 4; ++n_)                                       \
      BS[n_] = *(const short8*)(bq + ((size_t)n_*K5 + (kt))*512);        \
  } while (0)

#define MFMA32(AS, BS) do {                                              \
    __builtin_amdgcn_s_setprio(1);                                       \
    _Pragma("unroll")                                                    \
    for (int m_ = 0; m_ < 8; ++m_)                                       \
      _Pragma("unroll")                                                  \
      for (int n_ = 0; n_ < 4; ++n_)                                     \
        acc[m_][n_] = __builtin_amdgcn_mfma_f32_16x16x32_bf16(BS[n_], AS[m_], acc[m_][n_], 0,0,0); \
    __builtin_amdgcn_s_setprio(0);                                       \
  } while (0)

  const int nk = K >> 5;   // even, >= 4

  // prologue: Bg(0)->b0 (4), stageA(0) (2), stageA(1) (2); certify Bg(0)+stA(0)
  BGLOAD(b0, 0);
  stageA(0); stageA(1);
  asm volatile("s_waitcnt vmcnt(2)" ::: "memory");
  __builtin_amdgcn_s_barrier();
  asm volatile("" ::: "memory");
  AREADS(a0, 0);

  for (int kt = 0; kt < nk; kt += 2) {
    // ---- even tile kt: issue stA(kt+2), Bg(kt+1); certify stA(kt+1)+Bg(kt) ----
    if (kt + 2 < nk) stageA(kt + 2);
    BGLOAD(b1, kt + 1);
    if (kt + 2 < nk) asm volatile("s_waitcnt vmcnt(6)" ::: "memory");
    else             asm volatile("s_waitcnt vmcnt(4)" ::: "memory");
    __builtin_amdgcn_s_barrier();
    asm volatile("" ::: "memory");
    AREADS(a1, (kt+1) & 3);
    __builtin_amdgcn_sched_barrier(0);
    MFMA32(a0, b0);

    // ---- odd tile kt+1: issue stA(kt+3), Bg(kt+2); certify stA(kt+2)+Bg(kt+1) ----
    if (kt + 2 < nk) {
      if (kt + 3 < nk) stageA(kt + 3);
      BGLOAD(b0, kt + 2);
      if (kt + 3 < nk) asm volatile("s_waitcnt vmcnt(6)" ::: "memory");
      else             asm volatile("s_waitcnt vmcnt(4)" ::: "memory");
      __builtin_amdgcn_s_barrier();
      asm volatile("" ::: "memory");
      AREADS(a0, (kt+2) & 3);
      __builtin_amdgcn_sched_barrier(0);
    } else {
      asm volatile("s_waitcnt vmcnt(0)" ::: "memory");
      __builtin_amdgcn_s_barrier();
      asm volatile("" ::: "memory");
    }
    MFMA32(a1, b1);
  }

#undef AREADS
#undef BGLOAD
#undef MFMA32

  // ---- epilogue: lane&15 = M-row, (lane>>4)*4+r = N-col -> vector stores ----
  #pragma unroll
  for (int m = 0; m < 8; ++m) {
    const int rowg = by*256 + wr*128 + m*16 + fr;
    #pragma unroll
    for (int n = 0; n < 4; ++n) {
      const int colg = bx*256 + wc*64 + n*16 + fq*4;
      const float4 bv = *(const float4*)&bias[colg];
      float v0 = acc[m][n][0] + bv.x;
      float v1 = acc[m][n][1] + bv.y;
      float v2 = acc[m][n][2] + bv.z;
      float v3 = acc[m][n][3] + bv.w;
      if (EPI == 0) {
        #define GELU(v) do { \
          float u_ = 0.7978845608028654f*((v) + 0.044715f*(v)*(v)*(v)); \
          float e_ = __builtin_amdgcn_exp2f(-2.8853900817779268f*u_);   \
          (v) = (v) * __builtin_amdgcn_rcpf(1.0f + e_); } while(0)
        GELU(v0); GELU(v1); GELU(v2); GELU(v3);
        #undef GELU
        ushort4 o; o.x = f2bf(v0); o.y = f2bf(v1); o.z = f2bf(v2); o.w = f2bf(v3);
        *(ushort4*)&outb[(size_t)rowg*N + colg] = o;
      } else {
        float4 o; o.x = v0; o.y = v1; o.z = v2; o.w = v3;
        *(float4*)&outf[(size_t)rowg*N + colg] = o;
      }
    }
  }
}

extern "C" void kernel_launch(void* const* d_in, const int* in_sizes, int n_in,
                              void* d_out, int out_size, void* d_ws, size_t ws_size,
                              hipStream_t stream)
{
  const float* hid  = (const float*)d_in[0];
  const float* Wfc  = (const float*)d_in[1];
  const float* bfc  = (const float*)d_in[2];
  const float* Wpj  = (const float*)d_in[3];
  const float* bpj  = (const float*)d_in[4];
  const float* Amat = (const float*)d_in[5];
  const float* Bmat = (const float*)d_in[6];
  const float* Cmat = (const float*)d_in[7];
  const float* Dmat = (const float*)d_in[8];

  float* out = (float*)d_out;                  // [TOK][HID]
  float* ab  = out + (size_t)TOK*HID;          // [TOK][INTER]
  float* cd  = ab  + (size_t)TOK*INTER;        // [TOK][HID]

  char* ws = (char*)d_ws;
  ushort* hidb = (ushort*)ws;  ws += (size_t)TOK*HID*2;
  ushort* bpk1 = (ushort*)ws;  ws += (size_t)HID*INTER*2;   // packed W_fc
  ushort* bpk2 = (ushort*)ws;  ws += (size_t)INTER*HID*2;   // packed W_proj
  ushort* hbf  = (ushort*)ws;  ws += (size_t)TOK*INTER*2;
  ushort* apk  = (ushort*)ws;  ws += (size_t)HID*16*2;
  ushort* cpk  = (ushort*)ws;  ws += (size_t)INTER*16*2;
  float*  tpab = (float*)ws;   ws += (size_t)NPART*TOK*16*4;
  float*  tpcd = (float*)ws;   ws += (size_t)NPART*TOK*16*4;

  // independent pre-passes
  cvt_f32_bf16<<<4096, 256, 0, stream>>>(hid, hidb, TOK*HID/4);
  {
    int tot1 = (INTER/16)*(HID/32)*64;   // pack W_fc [HID][INTER], K=HID (k5sh=6)
    pack_b<<<(tot1 + 255)/256, 256, 0, stream>>>(Wfc, bpk1, INTER, 6, tot1);
    int tot2 = (HID/16)*(INTER/32)*64;   // pack W_proj [INTER][HID], K=INTER (k5sh=8)
    pack_b<<<(tot2 + 255)/256, 256, 0, stream>>>(Wpj, bpk2, HID, 8, tot2);
  }
  pack_w<<<((HID/32)*64 + 255)/256, 256, 0, stream>>>(Amat, apk, HID);
  pack_w<<<((INTER/32)*64 + 255)/256, 256, 0, stream>>>(Cmat, cpk, INTER);

  // t_ab partials = hidden @ A
  lora_in_mfma<<<(TOK/16)*NPART/4, 256, 0, stream>>>(hidb, apk, tpab, TOK, HID);

  // h = gelu(hidden @ W_fc + b_fc), stored bf16
  gemm_bt<0><<<(TOK/256)*(INTER/256), 512, 0, stream>>>(
      hidb, bpk1, bfc, hbf, nullptr, TOK, INTER, HID, INTER/256);

  // ab_out = (hidden @ A) @ B
  lora_out<<<dim3(INTER/1024, TOK/8), 256, 0, stream>>>(tpab, Bmat, ab, INTER, TOK);

  // cd_out = (h @ C) @ D
  lora_in_mfma<<<(TOK/16)*NPART/4, 256, 0, stream>>>(hbf, cpk, tpcd, TOK, INTER);
  lora_out<<<dim3(HID/1024, TOK/8), 256, 0, stream>>>(tpcd, Dmat, cd, HID, TOK);

  // out = h @ W_proj + b_proj
  gemm_bt<1><<<(TOK/256)*(HID/256), 512, 0, stream>>>(
      hbf, bpk2, bpj, nullptr, out, TOK, HID, INTER, HID/256);
}